// Round 3
// baseline (731.872 us; speedup 1.0000x reference)
//
#include <hip/hip_runtime.h>
#include <hip/hip_bf16.h>

// GruDirection3d forward, d1=d2=d3=1. B=2, C=96, D=H=W=32.
// out[b,c,d,y,x] = z*h_tilde + (1-z)*out[b,c,d-1,y-1,x-1], border = h0.
//
// Pipelined plane-wavefront DP, 4 y-strips per slab:
//   grid = 192 slabs x 4 strips = 768 blocks (3/CU on 256 CUs), 256 thr/block.
//   Strip q owns rows [8q, 8q+8). Thread (yl,x) computes one element per
//   d-plane. Intra-strip prev-plane values live in double-buffered LDS
//   (stride-1 reads, conflict-free). The strip boundary (producer's row
//   8q+7 of plane d-1) is read from global `out`, synchronized via a
//   monotone counter in d_ws: producer's wave 3 does a release atomicAdd
//   (wave-level vmcnt(0) drain covers its row-7 out stores); consumer's
//   row-0 lanes acquire-spin, then agent-scope atomic loads of the row
//   (cross-XCD safe per Guideline 16). Skew = 3 steps only.

#define PLANE 1024
#define DD 32
#define NSTRIP 4
#define SROWS 8               // rows per strip

__global__ __launch_bounds__(256) void gru3d_pipe(
    const float* __restrict__ z,
    const float* __restrict__ ht,
    const float* __restrict__ h0p,
    float* __restrict__ out,
    int* __restrict__ cnt)    // [192][3] monotone publish counters, zeroed
{
    const int blk = blockIdx.x;          // bc*4 + q  (consumer right after producer)
    const int bc  = blk >> 2;
    const int q   = blk & 3;
    const int tid = threadIdx.x;
    const int yl  = tid >> 5;            // 0..7
    const int x   = tid & 31;
    const int gy  = q * SROWS + yl;      // global row
    const float h0 = h0p[0];

    const size_t slab = (size_t)bc * (DD * PLANE);
    const float* zb = z   + slab;
    const float* tb = ht  + slab;
    float*       ob = out + slab;
    const int off = gy * 32 + x;         // offset within a plane

    __shared__ float buf[2][SROWS * 32];

    int* mycnt  = cnt + bc * 3 + ((q > 0) ? (q - 1) : 0);  // consumed if q>0
    int* pubcnt = cnt + bc * 3 + ((q < 3) ? q : 0);        // published if q<3

    // Prefetch planes d=0, d=1 (1 element/thread each).
    float zA = zb[off],          tA = tb[off];
    float zB = zb[PLANE + off],  tB = tb[PLANE + off];

    // d = 0: predecessor plane is the h0 border everywhere.
    float h = zA * tA + (1.0f - zA) * h0;
    ob[off] = h;
    buf[0][tid] = h;
    if (q < 3 && tid == 255)   // wave 3: vmcnt(0) drain covers row-7 stores
        __hip_atomic_fetch_add(pubcnt, 32, __ATOMIC_RELEASE, __HIP_MEMORY_SCOPE_AGENT);
    __syncthreads();

    for (int d = 1; d < DD; ++d) {
        zA = zB; tA = tB;
        if (d + 1 < DD) {                          // prefetch plane d+1 early
            zB = zb[(d + 1) * PLANE + off];
            tB = tb[(d + 1) * PLANE + off];
        }
        float pv;
        if (yl == 0) {
            if (q == 0) {
                pv = h0;                           // gy==0: border
            } else {
                // need producer's plane d-1 published: cnt >= 32*d
                while (__hip_atomic_load(mycnt, __ATOMIC_ACQUIRE,
                                         __HIP_MEMORY_SCOPE_AGENT) < 32 * d)
                    __builtin_amdgcn_s_sleep(1);
                if (x > 0) {
                    const float* src = ob + (d - 1) * PLANE + (gy - 1) * 32 + (x - 1);
                    pv = __hip_atomic_load(src, __ATOMIC_RELAXED,
                                           __HIP_MEMORY_SCOPE_AGENT);
                } else {
                    pv = h0;
                }
            }
        } else {
            pv = (x > 0) ? buf[(d - 1) & 1][(yl - 1) * 32 + (x - 1)] : h0;
        }
        h = zA * tA + (1.0f - zA) * pv;
        ob[d * PLANE + off] = h;
        buf[d & 1][tid] = h;
        if (q < 3 && tid == 255)
            __hip_atomic_fetch_add(pubcnt, 32, __ATOMIC_RELEASE, __HIP_MEMORY_SCOPE_AGENT);
        __syncthreads();
    }
}

extern "C" void kernel_launch(void* const* d_in, const int* in_sizes, int n_in,
                              void* d_out, int out_size, void* d_ws, size_t ws_size,
                              hipStream_t stream) {
    const float* z  = (const float*)d_in[0];
    const float* ht = (const float*)d_in[1];
    const float* h0 = (const float*)d_in[2];
    float* out      = (float*)d_out;
    int*   cnt      = (int*)d_ws;        // 192*3 ints

    // d_ws is poisoned 0xAA before every launch — zero the counters.
    hipMemsetAsync(cnt, 0, 4096, stream);

    const int BC = 2 * 96;
    gru3d_pipe<<<dim3(BC * NSTRIP), dim3(256), 0, stream>>>(z, ht, h0, out, cnt);
}

// Round 4
// 104.748 us; speedup vs baseline: 6.9870x; 6.9870x over previous
//
#include <hip/hip_runtime.h>
#include <hip/hip_bf16.h>

// GruDirection3d forward, d1=d2=d3=1. B=2, C=96, D=H=W=32.
// out[b,c,d,y,x] = z*h_tilde + (1-z)*out[b,c,d-1,y-1,x-1], border = h0.
//
// Plane-wavefront DP, one block per (b,c) slab (192 blocks, no cross-block
// sync — R3 showed agent-scope handoff convoys at ~24 us/step).
// 512 threads, float2 per thread. Prev plane double-buffered in LDS
// (row stride 33 to break the stride-2 bank pattern). Key change vs R2:
// raw `s_waitcnt lgkmcnt(0); s_barrier` instead of __syncthreads — the
// compiler's vmcnt(0) drain before s_barrier was forcing out-store and
// prefetch-load completion every step (m97 barrier-drain effect). Global
// prefetch depth 2 gives ~2 steps of slack over HBM latency.

#define P2   512               // float2 elements per plane
#define DD   32
#define ROWP 33                // padded LDS row stride (floats)

#define BAR() asm volatile("s_waitcnt lgkmcnt(0)\n\ts_barrier" ::: "memory")

__global__ __launch_bounds__(512) void gru3d_wf2(
    const float* __restrict__ z,
    const float* __restrict__ ht,
    const float* __restrict__ h0p,
    float* __restrict__ out)
{
    __shared__ float buf[2][32 * ROWP];

    const int bc  = blockIdx.x;          // 0..191
    const int tid = threadIdx.x;         // 0..511
    const int y   = tid >> 4;            // 0..31
    const int xt  = tid & 15;            // 0..15 (float2 column)
    const int x0  = xt * 2;
    const float h0 = h0p[0];

    const size_t slab = (size_t)bc * (DD * 2 * P2);
    const float2* zv = (const float2*)(z  + slab);
    const float2* tv = (const float2*)(ht + slab);
    float2*       ov = (float2*)(out + slab);
    const int off = y * 16 + xt;

    // Prefetch planes 0,1,2.
    float2 zA = zv[off],          tA = tv[off];
    float2 zB = zv[P2 + off],     tB = tv[P2 + off];
    float2 zC = zv[2 * P2 + off], tC = tv[2 * P2 + off];

    // d = 0: predecessor is the h0 border everywhere.
    float2 h;
    h.x = zA.x * tA.x + (1.0f - zA.x) * h0;
    h.y = zA.y * tA.y + (1.0f - zA.y) * h0;
    ov[off] = h;
    buf[0][y * ROWP + x0]     = h.x;
    buf[0][y * ROWP + x0 + 1] = h.y;
    BAR();

    for (int d = 1; d < DD; ++d) {
        // Issue prefetch for plane d+2 (clamped; redundant tail loads are L1 hits).
        const int dn = (d + 2 < DD) ? (d + 2) : (DD - 1);
        float2 zN = zv[dn * P2 + off], tN = tv[dn * P2 + off];

        const float* pb = buf[(d - 1) & 1];
        float2 pv;
        if (y > 0) {
            pv.x = (x0 > 0) ? pb[(y - 1) * ROWP + x0 - 1] : h0;
            pv.y = pb[(y - 1) * ROWP + x0];
        } else {
            pv.x = h0; pv.y = h0;
        }

        h.x = zB.x * tB.x + (1.0f - zB.x) * pv.x;
        h.y = zB.y * tB.y + (1.0f - zB.y) * pv.y;
        ov[d * P2 + off] = h;

        float* cb = buf[d & 1];
        cb[y * ROWP + x0]     = h.x;
        cb[y * ROWP + x0 + 1] = h.y;

        zB = zC; tB = tC; zC = zN; tC = tN;
        BAR();
    }
}

extern "C" void kernel_launch(void* const* d_in, const int* in_sizes, int n_in,
                              void* d_out, int out_size, void* d_ws, size_t ws_size,
                              hipStream_t stream) {
    const float* z  = (const float*)d_in[0];
    const float* ht = (const float*)d_in[1];
    const float* h0 = (const float*)d_in[2];
    float* out      = (float*)d_out;

    const int BC = 2 * 96;               // 192 slabs, one block each
    gru3d_wf2<<<dim3(BC), dim3(512), 0, stream>>>(z, ht, h0, out);
}

// Round 5
// 103.580 us; speedup vs baseline: 7.0657x; 1.0113x over previous
//
#include <hip/hip_runtime.h>
#include <hip/hip_bf16.h>

// GruDirection3d forward, d1=d2=d3=1. B=2, C=96, D=H=W=32.
// out[b,c,d,y,x] = z*h_tilde + (1-z)*out[b,c,d-1,y-1,x-1], border = h0.
//
// Register-resident plane wavefront: ONE WAVE per (b,c) slab (192 blocks of
// 64 threads). Lane L = (y = L>>1, xh = L&1) owns the 16-float row segment
// x in [16*xh, 16*xh+16). The whole 32x32 plane lives in 16 VGPRs/lane.
// The (y-1, x-1) predecessor is built with cross-lane shuffles:
//   s[i]  = shfl_up(h[i], 2)   -> (y-1, same segment), element i
//   bnd   = shfl_up(h[15], 3)  -> (y-1, other segment) element 15 (x=15)
//   pv[i] = i>0 ? s[i-1] : (xh ? bnd : h0);  y==0 -> h0 everywhere.
// No LDS, no barriers — removes the per-step barrier+LDS critical path of
// R2/R4. Global loads are depth-2 prefetched dwordx4 (16 KB in flight/wave
// covers HBM latency per Little's law); stores are fire-and-forget.
// Fully unrolled so all arrays are SSA -> VGPRs.

#define DD 32

#define UNPACK16(dst, src)                                                   \
    dst[0]=src[0].x;  dst[1]=src[0].y;  dst[2]=src[0].z;  dst[3]=src[0].w;   \
    dst[4]=src[1].x;  dst[5]=src[1].y;  dst[6]=src[1].z;  dst[7]=src[1].w;   \
    dst[8]=src[2].x;  dst[9]=src[2].y;  dst[10]=src[2].z; dst[11]=src[2].w;  \
    dst[12]=src[3].x; dst[13]=src[3].y; dst[14]=src[3].z; dst[15]=src[3].w;

__global__ __launch_bounds__(64) void gru3d_reg(
    const float* __restrict__ zg,
    const float* __restrict__ tg,
    const float* __restrict__ h0p,
    float* __restrict__ og)
{
    const int L  = threadIdx.x;          // 0..63
    const int bc = blockIdx.x;           // 0..191
    const int xh = L & 1;
    const bool top = (L < 2);            // y == 0
    const float h0 = h0p[0];

    const size_t b4 = (size_t)bc * (DD * 256) + (size_t)L * 4;  // float4 units
    const float4* zv = (const float4*)zg + b4;
    const float4* tv = (const float4*)tg + b4;
    float4*       ov = (float4*)og + b4;

    float4 zq[3][4], tq[3][4];           // 3-plane rotating prefetch buffers
    #pragma unroll
    for (int p = 0; p < 3; ++p) {
        #pragma unroll
        for (int i = 0; i < 4; ++i) {
            zq[p][i] = zv[p * 256 + i];
            tq[p][i] = tv[p * 256 + i];
        }
    }

    float h[16];

    // d = 0: predecessor plane is the h0 border everywhere.
    {
        float zc[16], tc[16];
        UNPACK16(zc, zq[0]); UNPACK16(tc, tq[0]);
        #pragma unroll
        for (int i = 0; i < 16; ++i)
            h[i] = zc[i] * tc[i] + (1.0f - zc[i]) * h0;
        #pragma unroll
        for (int i = 0; i < 4; ++i)
            ov[i] = make_float4(h[4*i], h[4*i+1], h[4*i+2], h[4*i+3]);
    }

    #pragma unroll
    for (int d = 1; d < DD; ++d) {
        const int cur = d % 3;
        const int nxt = (d + 2) % 3;
        if (d + 2 < DD) {                // prefetch plane d+2 into freed buffer
            #pragma unroll
            for (int i = 0; i < 4; ++i) {
                zq[nxt][i] = zv[(d + 2) * 256 + i];
                tq[nxt][i] = tv[(d + 2) * 256 + i];
            }
        }

        // Predecessor values via cross-lane shuffles of previous h.
        float s[16];
        #pragma unroll
        for (int i = 0; i < 16; ++i) s[i] = __shfl_up(h[i], 2, 64);
        float bnd = __shfl_up(h[15], 3, 64);

        float zc[16], tc[16];
        UNPACK16(zc, zq[cur]); UNPACK16(tc, tq[cur]);

        float hn[16];
        {
            float pv0 = top ? h0 : (xh ? bnd : h0);
            hn[0] = zc[0] * tc[0] + (1.0f - zc[0]) * pv0;
        }
        #pragma unroll
        for (int i = 1; i < 16; ++i) {
            float pv = top ? h0 : s[i - 1];
            hn[i] = zc[i] * tc[i] + (1.0f - zc[i]) * pv;
        }
        #pragma unroll
        for (int i = 0; i < 16; ++i) h[i] = hn[i];

        #pragma unroll
        for (int i = 0; i < 4; ++i)
            ov[d * 256 + i] = make_float4(h[4*i], h[4*i+1], h[4*i+2], h[4*i+3]);
    }
}

extern "C" void kernel_launch(void* const* d_in, const int* in_sizes, int n_in,
                              void* d_out, int out_size, void* d_ws, size_t ws_size,
                              hipStream_t stream) {
    const float* z  = (const float*)d_in[0];
    const float* ht = (const float*)d_in[1];
    const float* h0 = (const float*)d_in[2];
    float* out      = (float*)d_out;

    const int BC = 2 * 96;               // 192 slabs, one wave each
    gru3d_reg<<<dim3(BC), dim3(64), 0, stream>>>(z, ht, h0, out);
}